// Round 3
// baseline (299.818 us; speedup 1.0000x reference)
//
#include <hip/hip_runtime.h>
#include <hip/hip_bf16.h>

typedef __bf16 bf16_t;
typedef bf16_t bf16x8 __attribute__((ext_vector_type(8)));
typedef bf16_t bf16x4 __attribute__((ext_vector_type(4)));
typedef float  f32x4  __attribute__((ext_vector_type(4)));

#define BM 256
#define BN 256
#define BK 64   // one K-tile; a row is 8 chunks of 8 bf16 (16B each)

enum { EPI_NONE = 0, EPI_THRESH = 1, EPI_BIAS = 2 };

__device__ __forceinline__ void memfence() { asm volatile("" ::: "memory"); }
__device__ __forceinline__ void blockbar() {
    memfence(); __builtin_amdgcn_s_barrier(); memfence();
}

#define GLD16(src, dst) __builtin_amdgcn_global_load_lds( \
    (const __attribute__((address_space(1))) void*)(src), \
    (__attribute__((address_space(3))) void*)(dst), 16, 0, 0)

// 256x256 tile, BK=64, 512 threads = 8 waves (2M x 4N), per-wave C = 128x64.
// LDS intensity 42.7 FLOP/B (vs 32 at 64x64/wave) -> LDS-read time ~= MFMA
// time, so overlap can hide it. 4 sub-phases per K-tile over C-quadrants
// (64x32 each, snake order), each phase:
//   {ds_read subtile ; [stage] ; barrier ; lgkmcnt(0)+sched_barrier ;
//    setprio(1) ; 16 MFMA ; setprio(0) ; barrier}
// Staging: ALL 8 global_load_lds for tile t+1 issued at phase 0 of tile t
// (issue-early, T14) into the buffer freed at end of tile t-1; the vmcnt(0)
// at the phase-3 boundary is ~3 phases after issue, so HBM latency is fully
// covered and the "drain" retires immediately.
// LDS swizzle: chunk ^= (row&7) on the GLOBAL side of global_load_lds (LDS
// stays linear, satisfying the wave-uniform-base rule); fragment
// ds_read_b128s then conflict at most 2-way (free) -- measured 0 conflicts.
template <int EPI, typename CT>
__device__ __forceinline__
void gemm_tile(const bf16_t* __restrict__ A, const bf16_t* __restrict__ B,
               CT* __restrict__ C, const float* __restrict__ bias,
               int m0, int n0, int N, int K,
               bf16_t* __restrict__ As, bf16_t* __restrict__ Bs)
{
    const int lane = threadIdx.x & 63;
    const int wave = threadIdx.x >> 6;   // 0..7
    const int wm = wave >> 2;            // 0..1 : 128-row band of A
    const int wn = wave & 3;             // 0..3 : 64-col band of B

    const int fm  = lane & 15;
    const int ql  = lane >> 4;
    const int fsw = fm & 7;

    const int NT = K / BK;               // 12 for K=768

    // per-lane global staging bases: wave covers rows (wave*2+l)*8..+7 of each
    // 128-row half; chunk pre-swizzled so linear LDS ends up XOR-swizzled.
    const int choff = ((lane & 7) ^ ((lane >> 3) & 7)) * 8;
    const bf16_t* pA[2]; const bf16_t* pB[2];
    int sd[2];                            // LDS 16B-unit base per slot
#pragma unroll
    for (int l = 0; l < 2; ++l) {
        const int r = (wave * 2 + l) * 8 + (lane >> 3);
        pA[l] = A + (size_t)(m0 + r) * K + choff;
        pB[l] = B + (size_t)(n0 + r) * K + choff;
        sd[l] = (wave * 2 + l) * 64;
    }

#define STAGE_TILE(tt, Ad, Bd) do {                                          \
    _Pragma("unroll") for (int h_ = 0; h_ < 2; ++h_)                         \
    _Pragma("unroll") for (int l_ = 0; l_ < 2; ++l_) {                       \
        GLD16(pA[l_] + (size_t)h_ * 128 * K + (size_t)(tt) * BK,             \
              (Ad) + (size_t)(h_ * 1024 + sd[l_]) * 8);                      \
        GLD16(pB[l_] + (size_t)h_ * 128 * K + (size_t)(tt) * BK,             \
              (Bd) + (size_t)(h_ * 1024 + sd[l_]) * 8);                      \
    } } while (0)

#define LOAD_A(mh) do {                                                      \
    _Pragma("unroll") for (int i_ = 0; i_ < 4; ++i_)                         \
    _Pragma("unroll") for (int k_ = 0; k_ < 2; ++k_)                         \
        af[i_][k_] = *(const bf16x8*)(Ab + (size_t)(                         \
            (wm * 128 + (mh) * 64 + i_ * 16 + fm) * 8 +                      \
            ((k_ * 4 + ql) ^ fsw)) * 8); } while (0)

#define LOAD_B(nh) do {                                                      \
    _Pragma("unroll") for (int j_ = 0; j_ < 2; ++j_)                         \
    _Pragma("unroll") for (int k_ = 0; k_ < 2; ++k_)                         \
        bfx[j_][k_] = *(const bf16x8*)(Bb + (size_t)(                        \
            (wn * 64 + (nh) * 32 + j_ * 16 + fm) * 8 +                       \
            ((k_ * 4 + ql) ^ fsw)) * 8); } while (0)

#define MFMA_Q(mh, nh) do {                                                  \
    _Pragma("unroll") for (int i_ = 0; i_ < 4; ++i_)                         \
    _Pragma("unroll") for (int j_ = 0; j_ < 2; ++j_)                         \
    _Pragma("unroll") for (int k_ = 0; k_ < 2; ++k_)                         \
        acc[(mh) * 4 + i_][(nh) * 2 + j_] =                                  \
            __builtin_amdgcn_mfma_f32_16x16x32_bf16(                         \
                af[i_][k_], bfx[j_][k_],                                     \
                acc[(mh) * 4 + i_][(nh) * 2 + j_], 0, 0, 0); } while (0)

#define PHASE_TAIL(mh, nh) do {                                              \
    blockbar();                                                              \
    asm volatile("s_waitcnt lgkmcnt(0)" ::: "memory");                       \
    __builtin_amdgcn_sched_barrier(0);                                       \
    __builtin_amdgcn_s_setprio(1);                                           \
    MFMA_Q(mh, nh);                                                          \
    __builtin_amdgcn_s_setprio(0);                                           \
    blockbar(); } while (0)

    f32x4 acc[8][4];
#pragma unroll
    for (int i = 0; i < 8; ++i)
#pragma unroll
        for (int j = 0; j < 4; ++j) acc[i][j] = (f32x4){0.f, 0.f, 0.f, 0.f};

    // prologue: stage tile 0 -> buf0, drain (once), barrier
    STAGE_TILE(0, As, Bs);
    asm volatile("s_waitcnt vmcnt(0)" ::: "memory");
    blockbar();

    for (int t = 0; t < NT; ++t) {
        const int cur = t & 1;
        const bf16_t* __restrict__ Ab = As + cur * (BM * BK);
        const bf16_t* __restrict__ Bb = Bs + cur * (BN * BK);
        bf16_t* Asd = As + (cur ^ 1) * (BM * BK);
        bf16_t* Bsd = Bs + (cur ^ 1) * (BN * BK);

        bf16x8 af[4][2], bfx[2][2];

        // phase 0: quadrant (0,0); issue ALL next-tile staging (issue-early)
        LOAD_A(0); LOAD_B(0);
        if (t + 1 < NT) STAGE_TILE(t + 1, Asd, Bsd);
        PHASE_TAIL(0, 0);

        // phase 1: quadrant (0,1) -- af reused
        LOAD_B(1);
        PHASE_TAIL(0, 1);

        // phase 2: quadrant (1,1) -- bfx reused
        LOAD_A(1);
        PHASE_TAIL(1, 1);

        // phase 3: quadrant (1,0); tile t+1 must be landed before any wave
        // crosses into the next tile's reads (vmcnt + barrier => global)
        LOAD_B(0);
        asm volatile("s_waitcnt vmcnt(0)" ::: "memory");
        PHASE_TAIL(1, 0);
    }

    // epilogue: C/D layout col=lane&15, row=ql*4+r
#pragma unroll
    for (int mi = 0; mi < 8; ++mi) {
#pragma unroll
        for (int ni = 0; ni < 4; ++ni) {
            const int col = n0 + wn * 64 + ni * 16 + fm;
            float bv = 0.f;
            if (EPI == EPI_BIAS) bv = bias[col];
#pragma unroll
            for (int r = 0; r < 4; ++r) {
                const int row = m0 + wm * 128 + mi * 16 + ql * 4 + r;
                float v = acc[mi][ni][r];
                if (EPI == EPI_THRESH) v = (fabsf(v) > 1e-3f) ? v : 0.f;
                if (EPI == EPI_BIAS) v += bv;
                C[(size_t)row * N + col] = (CT)v;
            }
        }
    }

#undef STAGE_TILE
#undef LOAD_A
#undef LOAD_B
#undef MFMA_Q
#undef PHASE_TAIL
}

// dispatch 2: h = thresh(xb @ Ub^T) [blocks 0..383, bijective XCD swizzle;
// 384%8==0] and Wc = VTb @ Wt^T [blocks 384..392, 3x3 tiles of 256^2].
__global__ __launch_bounds__(512, 2)
void gemm_h_wc(const bf16_t* __restrict__ xb, const bf16_t* __restrict__ Ub,
               bf16_t* __restrict__ h,
               const bf16_t* __restrict__ VTb, const bf16_t* __restrict__ Wt,
               bf16_t* __restrict__ Wc)
{
    __shared__ __align__(16) bf16_t As[2 * BM * BK];   // 64 KiB
    __shared__ __align__(16) bf16_t Bs[2 * BN * BK];   // 64 KiB
    const int b = blockIdx.x;
    if (b < 384) {
        const int L = (b & 7) * 48 + (b >> 3);          // XCD-contiguous tiles
        gemm_tile<EPI_THRESH, bf16_t>(xb, Ub, h, nullptr,
                                      (L / 3) * BM, (L % 3) * BN, 768, 768, As, Bs);
    } else {
        const int b2 = b - 384;                          // 0..8
        gemm_tile<EPI_NONE, bf16_t>(VTb, Wt, Wc, nullptr,
                                    (b2 / 3) * BM, (b2 % 3) * BN, 768, 768, As, Bs);
    }
}

// dispatch 3: out = h @ Wc^T + bias (fp32 store)
__global__ __launch_bounds__(512, 2)
void gemm_out(const bf16_t* __restrict__ h, const bf16_t* __restrict__ Wc,
              float* __restrict__ out, const float* __restrict__ bias)
{
    __shared__ __align__(16) bf16_t As[2 * BM * BK];
    __shared__ __align__(16) bf16_t Bs[2 * BN * BK];
    const int b = blockIdx.x;
    const int L = (b & 7) * 48 + (b >> 3);
    gemm_tile<EPI_BIAS, float>(h, Wc, out, bias,
                               (L / 3) * BM, (L % 3) * BN, 768, 768, As, Bs);
}

// dispatch 1: all fp32->bf16 conversions + weight transpose in one kernel.
// blocks [0,24576): x cvt; [24576,25152): U; [25152,25728): VT; [25728,26304): w^T
__global__ __launch_bounds__(256)
void prep(const float* __restrict__ x, const float* __restrict__ U,
          const float* __restrict__ VT, const float* __restrict__ w,
          bf16_t* __restrict__ xb, bf16_t* __restrict__ Ub,
          bf16_t* __restrict__ VTb, bf16_t* __restrict__ Wt)
{
    __shared__ float tt[32][33];
    const int b = blockIdx.x;
    if (b < 25728) {
        const float* src; bf16_t* dst; int i;
        if (b < 24576)      { src = x;  dst = xb;  i = b * 256 + threadIdx.x; }
        else if (b < 25152) { src = U;  dst = Ub;  i = (b - 24576) * 256 + threadIdx.x; }
        else                { src = VT; dst = VTb; i = (b - 25152) * 256 + threadIdx.x; }
        const f32x4 v = ((const f32x4*)src)[i];
        bf16x4 o;
        o[0] = (bf16_t)v[0]; o[1] = (bf16_t)v[1];
        o[2] = (bf16_t)v[2]; o[3] = (bf16_t)v[3];
        ((bf16x4*)dst)[i] = o;
    } else {
        const int t = b - 25728;              // 0..575
        const int bx = (t % 24) * 32, by = (t / 24) * 32;
        const int tx = threadIdx.x & 31, ty = threadIdx.x >> 5;  // 32 x 8
#pragma unroll
        for (int i = 0; i < 32; i += 8)
            tt[ty + i][tx] = w[(size_t)(by + ty + i) * 768 + bx + tx];
        __syncthreads();
#pragma unroll
        for (int i = 0; i < 32; i += 8)
            Wt[(size_t)(bx + ty + i) * 768 + by + tx] = (bf16_t)tt[tx][ty + i];
    }
}

extern "C" void kernel_launch(void* const* d_in, const int* in_sizes, int n_in,
                              void* d_out, int out_size, void* d_ws, size_t ws_size,
                              hipStream_t stream)
{
    const float* x    = (const float*)d_in[0];   // (8,4096,768) fp32
    const float* w    = (const float*)d_in[1];   // (768,768) fp32
    const float* bias = (const float*)d_in[2];   // (768,) fp32
    const float* U    = (const float*)d_in[3];   // (768,768) fp32
    const float* VT   = (const float*)d_in[4];   // (768,768) fp32
    float* out = (float*)d_out;                  // (8,4096,768) fp32

    const int D = 768;
    const int M = 8 * 4096;                      // 32768
    const size_t MD = (size_t)M * D;
    const size_t DD = (size_t)D * D;

    char* ws = (char*)d_ws;
    bf16_t* xb  = (bf16_t*)ws;                         // MD bf16
    bf16_t* h   = (bf16_t*)(ws + MD * 2);              // MD bf16
    bf16_t* Ub  = (bf16_t*)(ws + MD * 4);              // DD
    bf16_t* VTb = (bf16_t*)(ws + MD * 4 + DD * 2);     // DD
    bf16_t* Wt  = (bf16_t*)(ws + MD * 4 + DD * 4);     // DD: weight^T
    bf16_t* Wc  = (bf16_t*)(ws + MD * 4 + DD * 6);     // DD: VT@weight

    // 1) conversions + transpose fused
    prep<<<26304, 256, 0, stream>>>(x, U, VT, w, xb, Ub, VTb, Wt);
    // 2) h = thresh(xb @ Ub^T)  +  Wc = (VT @ weight) in the same dispatch
    gemm_h_wc<<<384 + 9, 512, 0, stream>>>(xb, Ub, h, VTb, Wt, Wc);
    // 3) out = h @ Wc^T + bias  (== ((h @ W^T) @ VT^T) + bias)
    gemm_out<<<384, 512, 0, stream>>>(h, Wc, out, bias);
}